// Round 7
// baseline (372.891 us; speedup 1.0000x reference)
//
#include <hip/hip_runtime.h>

typedef __bf16 bf16;
typedef __bf16 bf16x4 __attribute__((ext_vector_type(4)));
typedef __bf16 bf16x8 __attribute__((ext_vector_type(8)));
typedef float  f32x4  __attribute__((ext_vector_type(4)));

// B=2, N=2048, QN=512, D=QD=1024, H=QH=16, HD=64. fp32 in/out, bf16 MFMA.

#define AS1(p) ((const __attribute__((address_space(1))) void*)(p))
#define AS3(p) ((__attribute__((address_space(3))) void*)(p))
__device__ __forceinline__ void gl16(const void* g, void* l) {
    __builtin_amdgcn_global_load_lds(AS1(g), AS3(l), 16, 0, 0);
}
// soft barriers: bounded per-wave vmcnt wait; prefetch loads stay in flight.
#define BAR_VM10() asm volatile("s_waitcnt vmcnt(10)\n\ts_barrier" ::: "memory")
#define BAR_VM8()  asm volatile("s_waitcnt vmcnt(8)\n\ts_barrier" ::: "memory")
#define BAR_VM4()  asm volatile("s_waitcnt vmcnt(4)\n\ts_barrier" ::: "memory")
#define BAR_VM3()  asm volatile("s_waitcnt vmcnt(3)\n\ts_barrier" ::: "memory")
#define BAR_VM0()  asm volatile("s_waitcnt vmcnt(0)\n\ts_barrier" ::: "memory")
#define BAR()      asm volatile("s_barrier" ::: "memory")

// ---------------------------------------------------------------------------
// fp32 -> bf16 cast for x and query
// ---------------------------------------------------------------------------
__global__ __launch_bounds__(256) void cast_bf16(
    const float* __restrict__ s0, bf16* __restrict__ d0, int n0,
    const float* __restrict__ s1, bf16* __restrict__ d1, int n1)
{
    int idx = (blockIdx.x * 256 + threadIdx.x) << 3;
    const float* s; bf16* d;
    if (idx < n0) { s = s0 + idx; d = d0 + idx; }
    else { int k = idx - n0; if (k >= n1) return; s = s1 + k; d = d1 + k; }
    f32x4 a = *(const f32x4*)s, c = *(const f32x4*)(s + 4);
    bf16x8 v;
#pragma unroll
    for (int j = 0; j < 4; j++) { v[j] = (bf16)a[j]; v[4 + j] = (bf16)c[j]; }
    *(bf16x8*)d = v;
}

// ---------------------------------------------------------------------------
// Weights [1024][N] fp32 -> bf16 transposed [N][1024]
// ---------------------------------------------------------------------------
__global__ __launch_bounds__(256) void wtrans(
    const float* __restrict__ S0, bf16* __restrict__ D0,
    const float* __restrict__ S1, bf16* __restrict__ D1,
    const float* __restrict__ S2, bf16* __restrict__ D2,
    const float* __restrict__ S3, bf16* __restrict__ D3,
    const float* __restrict__ S4, bf16* __restrict__ D4)
{
    __shared__ float T[64][65];
    int gx = blockIdx.x, k0 = blockIdx.y << 6;
    const float* S; bf16* D; int N;
    if (gx < 48)       { S = S0; D = D0; N = 3072; }
    else if (gx < 80)  { S = S1; D = D1; N = 2048; gx -= 48; }
    else if (gx < 128) { S = S2; D = D2; N = 3072; gx -= 80; }
    else if (gx < 144) { S = S3; D = D3; N = 1024; gx -= 128; }
    else               { S = S4; D = D4; N = 1024; gx -= 144; }
    int n0 = gx << 6, tid = threadIdx.x;
#pragma unroll
    for (int rr = 0; rr < 4; rr++) {
        int row = (rr << 4) + (tid >> 4), col = (tid & 15) << 2;
        f32x4 v = *(const f32x4*)(S + (size_t)(k0 + row) * N + n0 + col);
#pragma unroll
        for (int j = 0; j < 4; j++) T[col + j][row] = v[j];
    }
    __syncthreads();
    {
        int n = tid >> 2, kc = (tid & 3) << 4;
        bf16x8 v0, v1;
#pragma unroll
        for (int j = 0; j < 8; j++) {
            v0[j] = (bf16)T[n][kc + j];
            v1[j] = (bf16)T[n][kc + 8 + j];
        }
        bf16* dp = D + (size_t)(n0 + n) * 1024 + k0 + kc;
        *(bf16x8*)dp = v0; *(bf16x8*)(dp + 8) = v1;
    }
}

// ---------------------------------------------------------------------------
// GEMM: C[M,N] = A[M,K] @ Bt[N,K]^T, MT x 128 tile (MT=128 or 64), BK=32,
// LDS double-buffered global_load_lds staging, soft barriers.
// LDS swizzle: slot s of row r holds chunk s ^ ((r^(r>>2))&3)  (2-way, free).
// NSPLIT>0 (requires MT=128): epilogue scatters 64-col head-blocks into
// per-head buffers via LDS round-trip; vmask bit = write transposed
// [bh][hd][ntok]. s0scale multiplies split 0 (pre-scales Q for attention).
// ---------------------------------------------------------------------------
template <int MT, int NSPLIT, typename OT>
__global__ __launch_bounds__(256) void gemm_bt(
    const bf16* __restrict__ A, const bf16* __restrict__ Bt,
    OT* __restrict__ C0, OT* __restrict__ C1, OT* __restrict__ C2,
    OT* __restrict__ C3, OT* __restrict__ C4,
    const float* __restrict__ bias, int M, int N, int K, int tshift,
    float s0scale, unsigned vmask)
{
    __shared__ __align__(16) bf16 gsm[18432];   // 2 bufs @16KB stride; epilogue 4x4608

    constexpr int MB = MT / 32;        // acc m-blocks per wave (wave m-span MT/2)
    const int tid  = threadIdx.x;
    const int wave = tid >> 6, lane = tid & 63;
    const int l15  = lane & 15, g = lane >> 4;
    const int wr   = wave & 1, wc = wave >> 1;
    const int m0   = blockIdx.y * MT, n0 = blockIdx.x << 7;

    f32x4 acc[MB][4] = {};

    auto stage = [&](int t, int bsel) {
        const bf16* Ab = A  + (size_t)m0 * K + (t << 5);
        const bf16* Bb = Bt + (size_t)n0 * K + (t << 5);
        char* Ad = (char*)gsm + (bsel << 14);
        char* Bd = Ad + MT * 64;
        const int wb = (tid & 192) << 4;
#pragma unroll
        for (int i = 0; i < MT / 64; i++) {
            int L = (i << 8) + tid;
            int r = L >> 2, c = (L & 3) ^ ((r ^ (r >> 2)) & 3);
            gl16(Ab + (size_t)r * K + (c << 3), Ad + (i << 12) + wb);
        }
#pragma unroll
        for (int i = 0; i < 2; i++) {
            int L = (i << 8) + tid;
            int r = L >> 2, c = (L & 3) ^ ((r ^ (r >> 2)) & 3);
            gl16(Bb + (size_t)r * K + (c << 3), Bd + (i << 12) + wb);
        }
    };
    auto compute = [&](int bsel) {
        const char* Ad = (const char*)gsm + (bsel << 14);
        const char* Bd = Ad + MT * 64;
        bf16x8 af[MB], bq[4];
#pragma unroll
        for (int mb = 0; mb < MB; mb++) {
            int row = wr * (MT / 2) + (mb << 4) + l15;
            af[mb] = *(const bf16x8*)(Ad + (row << 6)
                      + ((g ^ ((row ^ (row >> 2)) & 3)) << 4));
        }
#pragma unroll
        for (int nb = 0; nb < 4; nb++) {
            int row = (wc << 6) + (nb << 4) + l15;
            bq[nb] = *(const bf16x8*)(Bd + (row << 6)
                      + ((g ^ ((row ^ (row >> 2)) & 3)) << 4));
        }
#pragma unroll
        for (int mb = 0; mb < MB; mb++)
#pragma unroll
            for (int nb = 0; nb < 4; nb++)
                acc[mb][nb] = __builtin_amdgcn_mfma_f32_16x16x32_bf16(
                    af[mb], bq[nb], acc[mb][nb], 0, 0, 0);
    };

    const int T = K >> 5;
    stage(0, 0);
    for (int t = 0; t < T; t++) {
        int bsel = t & 1;
        if (t + 1 < T) {
            stage(t + 1, bsel ^ 1);
            if constexpr (MT == 128) BAR_VM4(); else BAR_VM3();
        } else BAR_VM0();
        compute(bsel);
        BAR();
    }

    if constexpr (NSPLIT == 0) {
#pragma unroll
        for (int mb = 0; mb < MB; mb++)
#pragma unroll
            for (int nb = 0; nb < 4; nb++) {
                int n = n0 + (wc << 6) + (nb << 4) + l15;
                int mbase = m0 + wr * (MT / 2) + (mb << 4) + (g << 2);
                float bi = bias[n];
#pragma unroll
                for (int r = 0; r < 4; r++)
                    C0[(size_t)(mbase + r) * N + n] = (OT)(acc[mb][nb][r] + bi);
            }
    } else {
        BAR();
        bf16* stg = gsm + wave * 4608;
        const int nh = (n0 >> 6) + wc;
        const int sl = nh >> 4, hq = nh & 15;
        const float scl = (sl == 0) ? s0scale : 1.0f;
        const bool isv = (vmask >> sl) & 1;
        if (isv) {   // stage transposed [hd][t], stride 72
#pragma unroll
            for (int mb = 0; mb < MB; mb++)
#pragma unroll
                for (int nb = 0; nb < 4; nb++)
#pragma unroll
                    for (int r = 0; r < 4; r++)
                        stg[((nb << 4) + l15) * 72 + (mb << 4) + (g << 2) + r]
                            = (bf16)(acc[mb][nb][r] * scl);
        } else {     // stage [t][hd], stride 64
#pragma unroll
            for (int mb = 0; mb < MB; mb++)
#pragma unroll
                for (int nb = 0; nb < 4; nb++)
#pragma unroll
                    for (int r = 0; r < 4; r++)
                        stg[((mb << 4) + (g << 2) + r) << 6 | ((nb << 4) + l15)]
                            = (bf16)(acc[mb][nb][r] * scl);
        }
        __syncthreads();
        const int ntok = 1 << tshift;
        const int tok0 = m0 + wr * (MT / 2);
        const int b = tok0 >> tshift, t0 = tok0 & (ntok - 1);
        const int bh_ = (b << 4) + hq;
        OT* dst = (sl == 0) ? C0 : (sl == 1) ? C1 : (sl == 2) ? C2
                : (sl == 3) ? C3 : C4;
#pragma unroll
        for (int rr = 0; rr < 8; rr++) {
            int idx = (rr << 6) + lane;
            int rowi = idx >> 3, c = idx & 7;
            if (isv) {
                bf16x8 vv = *(const bf16x8*)&stg[rowi * 72 + (c << 3)];
                *(bf16x8*)&dst[((size_t)((bh_ << 6) + rowi)) * ntok + t0 + (c << 3)] = vv;
            } else {
                bf16x8 vv = *(const bf16x8*)&stg[(rowi << 6) + (c << 3)];
                *(bf16x8*)&dst[(((size_t)bh_ * ntok + t0 + rowi) << 6) + (c << 3)] = vv;
            }
        }
    }
}

// ---------------------------------------------------------------------------
// Flash attention, S^T form, fixed-max softmax (Q pre-scaled to log2 domain).
// QB = q 16-blocks per wave (2 -> q-tile 128, 1 -> q-tile 64).
// K staged in double-buffered LDS via global_load_lds (soft vmcnt barriers);
// V fragments loaded DIRECTLY global->registers from pre-transposed
// Vt [bh][64][ntok] (A-operand layout matches), eliminating V LDS traffic.
// NSEG=2: seg0 (K1/V1t) weighted tanh(gate[h]), seg1 weight 1.
// ---------------------------------------------------------------------------
template <int QB, int NSEG>
__global__ __launch_bounds__(256) void flash4(
    const bf16* __restrict__ Q,
    const bf16* __restrict__ K1, const bf16* __restrict__ V1t,
    const bf16* __restrict__ K2, const bf16* __restrict__ V2t,
    bf16* __restrict__ O, const float* __restrict__ gate,
    int nq, int nk1, int nk2)
{
    // K double-buf 2x8KB @elem 0; P strips @elem 8192 (4 waves x QB*1024 elems)
    __shared__ __align__(16) bf16 fsm[8192 + QB * 4096];

    const int tid = threadIdx.x;
    const int wave = tid >> 6, lane = tid & 63;
    const int l15 = lane & 15, g = lane >> 4;
    const int bh = blockIdx.y, h = bh & 15, b = bh >> 4;
    const int q0 = blockIdx.x * (QB * 64);
    const int T1 = nk1 >> 6, T2 = (NSEG == 2) ? (nk2 >> 6) : 0, T = T1 + T2;
    const int swzP = (l15 ^ (l15 >> 3)) & 7;

    char* Psw = (char*)fsm + 16384 + wave * (QB * 2048);

    // Q frags from global: B-operand, n=l15 (q), k=ks*32+g*8+j
    bf16x8 qf[QB][2];
#pragma unroll
    for (int qb = 0; qb < QB; qb++) {
        const bf16* qrow = Q + ((size_t)bh * nq + q0 + wave * (QB * 16) + (qb << 4) + l15) * 64;
        qf[qb][0] = *(const bf16x8*)(qrow + (g << 3));
        qf[qb][1] = *(const bf16x8*)(qrow + 32 + (g << 3));
    }

    f32x4 Oacc[4][QB] = {}, Ofin[4][QB] = {};
    float lcur[QB] = {};
    const float gmul = gate ? tanhf(gate[h]) : 1.0f;

    auto stageK = [&](int t, int bsel) {
        const bf16* kb = (NSEG == 1 || t < T1)
            ? K1 + ((size_t)bh * nk1 + (t << 6)) * 64
            : K2 + ((size_t)bh * nk2 + ((t - T1) << 6)) * 64;
        char* Kd = (char*)fsm + (bsel << 13);
        const int wb = (tid & 192) << 4;
#pragma unroll
        for (int i = 0; i < 2; i++) {
            int L = (i << 8) + tid;
            int r = L >> 3, c = (L & 7) ^ (r & 7);
            gl16(kb + (r << 6) + (c << 3), Kd + (i << 12) + wb);
        }
    };

    bf16x8 vf[4][2];   // V A-frags: [hd-block][k-chunk], loaded per tile
    auto loadV = [&](int t) {
        const bf16* vb; int stride;
        if (NSEG == 1 || t < T1) { vb = V1t + ((size_t)bh << 6) * nk1 + (t << 6); stride = nk1; }
        else { vb = V2t + ((size_t)bh << 6) * nk2 + ((t - T1) << 6); stride = nk2; }
#pragma unroll
        for (int hb = 0; hb < 4; hb++)
#pragma unroll
            for (int ks = 0; ks < 2; ks++)
                vf[hb][ks] = *(const bf16x8*)(vb + (size_t)((hb << 4) + l15) * stride
                                              + (ks << 5) + (g << 3));
    };

    auto compute = [&](int t, int bsel) {
        const char* Kb = (const char*)fsm + (bsel << 13);
        // S^T = K Q^T
        f32x4 S[4][QB];
#pragma unroll
        for (int nb = 0; nb < 4; nb++) {
            int row = (nb << 4) + l15;
            bf16x8 kf0 = *(const bf16x8*)(Kb + (row << 7) + ((g ^ (row & 7)) << 4));
            bf16x8 kf1 = *(const bf16x8*)(Kb + (row << 7) + (((4 + g) ^ (row & 7)) << 4));
#pragma unroll
            for (int qb = 0; qb < QB; qb++) {
                f32x4 s = {};
                s = __builtin_amdgcn_mfma_f32_16x16x32_bf16(kf0, qf[qb][0], s, 0, 0, 0);
                s = __builtin_amdgcn_mfma_f32_16x16x32_bf16(kf1, qf[qb][1], s, 0, 0, 0);
                S[nb][qb] = s;
            }
        }
        // exp2 + P store (P^T layout [q][k], swizzled) + row sums
        float rs[QB];
#pragma unroll
        for (int qb = 0; qb < QB; qb++) rs[qb] = 0.0f;
#pragma unroll
        for (int qb = 0; qb < QB; qb++)
#pragma unroll
            for (int nb = 0; nb < 4; nb++) {
                bf16x4 pv;
#pragma unroll
                for (int r = 0; r < 4; r++) {
                    float p = exp2f(S[nb][qb][r]);
                    rs[qb] += p;
                    pv[r] = (bf16)p;
                }
                *(bf16x4*)(Psw + (((qb << 4) + l15) << 7)
                    + ((((nb << 1) + (g >> 1)) ^ swzP) << 4) + ((g & 1) << 3)) = pv;
            }
#pragma unroll
        for (int qb = 0; qb < QB; qb++) {
            rs[qb] += __shfl_xor(rs[qb], 16);
            rs[qb] += __shfl_xor(rs[qb], 32);
            lcur[qb] += rs[qb];
        }
        // O^T += Vt @ P^T  (V frags already in registers)
        bf16x8 pf[QB][2];
#pragma unroll
        for (int qb = 0; qb < QB; qb++)
#pragma unroll
            for (int ks = 0; ks < 2; ks++)
                pf[qb][ks] = *(const bf16x8*)(Psw + (((qb << 4) + l15) << 7)
                              + ((((ks << 2) + g) ^ swzP) << 4));
#pragma unroll
        for (int hb = 0; hb < 4; hb++)
#pragma unroll
            for (int qb = 0; qb < QB; qb++) {
                Oacc[hb][qb] = __builtin_amdgcn_mfma_f32_16x16x32_bf16(vf[hb][0], pf[qb][0], Oacc[hb][qb], 0, 0, 0);
                Oacc[hb][qb] = __builtin_amdgcn_mfma_f32_16x16x32_bf16(vf[hb][1], pf[qb][1], Oacc[hb][qb], 0, 0, 0);
            }
        if (NSEG == 2 && t == T1 - 1) {   // gated-segment flush
#pragma unroll
            for (int qb = 0; qb < QB; qb++) {
                float w = gmul / lcur[qb];
#pragma unroll
                for (int hb = 0; hb < 4; hb++)
#pragma unroll
                    for (int r = 0; r < 4; r++) {
                        Ofin[hb][qb][r] += Oacc[hb][qb][r] * w;
                        Oacc[hb][qb][r] = 0.0f;
                    }
                lcur[qb] = 0.0f;
            }
        }
    };

    stageK(0, 0);
    for (int t = 0; t < T; t++) {
        int bsel = t & 1;
        loadV(t);                       // global->reg, latency hidden by S phase
        if (t + 1 < T) { stageK(t + 1, bsel ^ 1); BAR_VM10(); }
        else           { BAR_VM8(); }
        compute(t, bsel);
        BAR();                          // protect K buf reuse
    }

    float wfin[QB];
#pragma unroll
    for (int qb = 0; qb < QB; qb++)
        wfin[qb] = (NSEG == 2 ? 1.0f : gmul) / lcur[qb];

    // epilogue: O^T regs -> LDS [hd=64][q] (stride QB*64+8) -> coalesced stores
    constexpr int OST = QB * 64 + 8;
    bf16* OB = fsm;
#pragma unroll
    for (int hb = 0; hb < 4; hb++)
#pragma unroll
        for (int qb = 0; qb < QB; qb++)
#pragma unroll
            for (int r = 0; r < 4; r++) {
                float v = Oacc[hb][qb][r] * wfin[qb] + Ofin[hb][qb][r];
                OB[((hb << 4) + (g << 2) + r) * OST
                   + wave * (QB * 16) + (qb << 4) + l15] = (bf16)v;
            }
    __syncthreads();
    if constexpr (QB == 2) {
        int q = tid >> 1, half = (tid & 1) << 5;
        bf16x8 o[4];
#pragma unroll
        for (int j2 = 0; j2 < 4; j2++)
#pragma unroll
            for (int j = 0; j < 8; j++)
                o[j2][j] = OB[(half + (j2 << 3) + j) * OST + q];
        bf16* op = O + (((size_t)b * nq + q0 + q) << 10) + (h << 6) + half;
#pragma unroll
        for (int j2 = 0; j2 < 4; j2++)
            *(bf16x8*)(op + (j2 << 3)) = o[j2];
    } else {
        int q = tid >> 2, quarter = (tid & 3) << 4;
        bf16x8 o0, o1;
#pragma unroll
        for (int j = 0; j < 8; j++) {
            o0[j] = OB[(quarter + j) * OST + q];
            o1[j] = OB[(quarter + 8 + j) * OST + q];
        }
        bf16* op = O + (((size_t)b * nq + q0 + q) << 10) + (h << 6) + quarter;
        *(bf16x8*)op = o0;
        *(bf16x8*)(op + 8) = o1;
    }
}

// ---------------------------------------------------------------------------
// lr_out[b,i,j] = sum_k low_res[b,(i*64+k)&255,(i*64+k)>>8] * W[k,j] + bias[j]
// ---------------------------------------------------------------------------
__global__ __launch_bounds__(256) void lr_kernel(
    const float* __restrict__ low_res, const float* __restrict__ W,
    const float* __restrict__ bias, float* __restrict__ out)
{
    int idx = blockIdx.x * 256 + threadIdx.x;
    int j = idx & 63, i = (idx >> 6) & 255, b = idx >> 14;
    float acc = bias[j];
    const float* lr = low_res + ((size_t)b << 14);
    for (int k = 0; k < 64; k++) {
        int f = i * 64 + k;
        acc += lr[((f & 255) << 6) + (f >> 8)] * W[(k << 6) + j];
    }
    out[idx] = acc;
}

// ---------------------------------------------------------------------------
extern "C" void kernel_launch(void* const* d_in, const int* in_sizes, int n_in,
                              void* d_out, int out_size, void* d_ws, size_t ws_size,
                              hipStream_t stream)
{
    const float* x       = (const float*)d_in[0];
    const float* query   = (const float*)d_in[1];
    const float* lowres  = (const float*)d_in[2];
    const float* W_qkv   = (const float*)d_in[3];
    const float* W_xkv   = (const float*)d_in[4];
    const float* W_qlin  = (const float*)d_in[5];
    const float* gate    = (const float*)d_in[6];
    const float* W_proj  = (const float*)d_in[7];
    const float* b_proj  = (const float*)d_in[8];
    const float* W_qproj = (const float*)d_in[9];
    const float* b_qproj = (const float*)d_in[10];
    const float* W_lr    = (const float*)d_in[11];
    const float* b_lr    = (const float*)d_in[12];
    float* out = (float*)d_out;

    const float sc2 = 0.125f * 1.44269504088896f;   // scale*log2e, folded into Q

    char* ws = (char*)d_ws;
    bf16* WtX     = (bf16*)ws; ws += 10485760;  // [5120][1024] = qkv|xkv transposed
    bf16* Wtqlin  = (bf16*)ws; ws += 6291456;
    bf16* Wtproj  = (bf16*)ws; ws += 2097152;
    bf16* Wtqproj = (bf16*)ws; ws += 2097152;
    bf16* xb      = (bf16*)ws; ws += 8388608;   // ax aliases (xb dead by then)
    bf16* qryb    = (bf16*)ws; ws += 2097152;   // aq aliases
    bf16* qb      = (bf16*)ws; ws += 8388608;
    bf16* kb      = (bf16*)ws; ws += 8388608;
    bf16* vbt     = (bf16*)ws; ws += 8388608;   // [bh][64][2048]
    bf16* k2      = (bf16*)ws; ws += 8388608;
    bf16* v2t     = (bf16*)ws; ws += 8388608;   // [bh][64][2048]
    bf16* qq      = (bf16*)ws; ws += 2097152;
    bf16* qk      = (bf16*)ws; ws += 2097152;
    bf16* qvt     = (bf16*)ws; ws += 2097152;   // [bh][64][512]
    bf16* ax = xb;
    bf16* aq = qryb;

    cast_bf16<<<2560, 256, 0, stream>>>(x, xb, 4194304, query, qryb, 1048576);
    wtrans<<<dim3(160, 16), 256, 0, stream>>>(
        W_qkv, WtX, W_xkv, WtX + (size_t)3072 * 1024,
        W_qlin, Wtqlin, W_proj, Wtproj, W_qproj, Wtqproj);

    // x @ [W_qkv | W_xkv] -> q,k,v,k2,v2 in one pass (v, v2 transposed)
    gemm_bt<128, 5, bf16><<<dim3(40, 32), 256, 0, stream>>>(
        xb, WtX, qb, kb, vbt, k2, v2t, nullptr, 4096, 5120, 1024, 11, sc2, 0b10100u);
    // query @ W_qlin -> qq,qk,qv (qv transposed)
    gemm_bt<128, 3, bf16><<<dim3(24, 8), 256, 0, stream>>>(
        qryb, Wtqlin, qq, qk, qvt, nullptr, nullptr, nullptr, 1024, 3072, 1024, 9, sc2, 0b100u);

    // self-attention over x (q-tile 128)
    flash4<2, 1><<<dim3(16, 32), 256, 0, stream>>>(
        qb, kb, vbt, nullptr, nullptr, ax, nullptr, 2048, 2048, 0);
    // cross-attention (q-tile 64): gated x-KV segment + plain query-KV segment
    flash4<1, 2><<<dim3(8, 32), 256, 0, stream>>>(
        qq, k2, v2t, qk, qvt, aq, gate, 512, 2048, 512);

    // output projections (64-row tiles for 2x grid parallelism)
    gemm_bt<64, 0, float><<<dim3(8, 64), 256, 0, stream>>>(
        ax, Wtproj, out, nullptr, nullptr, nullptr, nullptr, b_proj,
        4096, 1024, 1024, 0, 1.0f, 0u);
    gemm_bt<64, 0, float><<<dim3(8, 16), 256, 0, stream>>>(
        aq, Wtqproj, out + 4194304, nullptr, nullptr, nullptr, nullptr, b_qproj,
        1024, 1024, 1024, 0, 1.0f, 0u);
    lr_kernel<<<128, 256, 0, stream>>>(lowres, W_lr, b_lr, out + 5242880);

    (void)in_sizes; (void)n_in; (void)out_size; (void)ws_size;
}